// Round 1
// baseline (465.602 us; speedup 1.0000x reference)
//
#include <hip/hip_runtime.h>

#define DD 128
#define HH 512
#define WW 512
#define NVOX (DD*HH*WW)          // 33554432
#define THRESHV 0.997f
#define KPEAKS 131072
#define CAND_CAP (1u<<19)        // 524288 candidate slots
#define PEAK_CAP (1u<<19)        // 524288 peak slots
#define NBINS 65536

// peaks all lie in (0.997, 1.0): float bits in [0x3F7F3B65, 0x3F7FFFFF],
// upper 16 bits constant 0x3F7F -> low 16 bits are monotone in value.
// bin = (~bits)&0xFFFF so ascending bin == descending value.

// ---------------- K0: init scratch (ws is poisoned 0xAA before every call)
__global__ void k_init(unsigned* counters, unsigned* hist, unsigned long long* sorted) {
    unsigned t = blockIdx.x * 256u + threadIdx.x;
    if (t < 64) counters[t] = 0u;
    if (t < NBINS) hist[t] = 0u;
    if (t < PEAK_CAP) sorted[t] = 0ull;
}

// ---------------- K1: stream volume, compact above-threshold candidates.
// 8192 blocks x 256 threads; each block handles 4096 voxels (4 float4/thread).
__global__ void k_cand(const float4* __restrict__ vol4, unsigned* counters, unsigned* cand) {
    __shared__ unsigned lcnt, lbase;
    __shared__ unsigned lbuf[4096];
    if (threadIdx.x == 0) lcnt = 0;
    __syncthreads();
    unsigned base4 = blockIdx.x * 1024u;   // in float4 units
#pragma unroll
    for (int i = 0; i < 4; i++) {
        unsigned f4 = base4 + i * 256u + threadIdx.x;
        float4 v = vol4[f4];
        unsigned vb = f4 * 4u;
        if (v.x > THRESHV) lbuf[atomicAdd(&lcnt, 1u)] = vb;
        if (v.y > THRESHV) lbuf[atomicAdd(&lcnt, 1u)] = vb + 1u;
        if (v.z > THRESHV) lbuf[atomicAdd(&lcnt, 1u)] = vb + 2u;
        if (v.w > THRESHV) lbuf[atomicAdd(&lcnt, 1u)] = vb + 3u;
    }
    __syncthreads();
    if (threadIdx.x == 0) lbase = atomicAdd(&counters[0], lcnt);
    __syncthreads();
    for (unsigned i = threadIdx.x; i < lcnt; i += 256u) {
        unsigned p = lbase + i;
        if (p < CAND_CAP) cand[p] = lbuf[i];
    }
}

// ---------------- K2: verify peaks (wave per candidate), emit 64-bit keys + histogram.
// peak iff vol[v] > THRESH and vol[v] >= all 7^3 in-bounds neighbors (equality allowed).
__global__ void k_peak(const float* __restrict__ vol, unsigned* counters,
                       const unsigned* __restrict__ cand, unsigned* hist,
                       unsigned long long* keys) {
    __shared__ unsigned lcnt, lbase;
    __shared__ unsigned long long lbuf[256];   // <= 4 waves * 64 iters max
    if (threadIdx.x == 0) lcnt = 0;
    __syncthreads();
    unsigned nc = counters[0]; if (nc > CAND_CAP) nc = CAND_CAP;
    int lane = threadIdx.x & 63;
    unsigned wv = (blockIdx.x * blockDim.x + threadIdx.x) >> 6;
    unsigned nw = (gridDim.x * blockDim.x) >> 6;
    for (unsigned c = wv; c < nc; c += nw) {
        unsigned idx = cand[c];
        int z = idx >> 18, y = (idx >> 9) & 511, x = idx & 511;
        float center = vol[idx];
        bool kill = false;
        for (int p = lane; p < 343; p += 64) {
            int dz = p / 49; int r = p - dz * 49; int dy = r / 7; int dx = r - dy * 7;
            int nz = z + dz - 3, ny = y + dy - 3, nx = x + dx - 3;
            if ((unsigned)nz < DD && (unsigned)ny < HH && (unsigned)nx < WW) {
                float v = vol[((unsigned)nz << 18) + ((unsigned)ny << 9) + (unsigned)nx];
                if (v > center) kill = true;
            }
        }
        if (!__any(kill) && lane == 0) {
            unsigned bits = __float_as_uint(center);
            atomicAdd(&hist[(~bits) & 0xFFFFu], 1u);
            lbuf[atomicAdd(&lcnt, 1u)] = ((unsigned long long)bits << 32) | idx;
        }
    }
    __syncthreads();
    if (threadIdx.x == 0) lbase = atomicAdd(&counters[1], lcnt);
    __syncthreads();
    for (unsigned i = threadIdx.x; i < lcnt; i += 256u) {
        unsigned p = lbase + i;
        if (p < PEAK_CAP) keys[p] = lbuf[i];
    }
}

// ---------------- K3: exclusive prefix sum over 65536 bins (single block).
__global__ void k_scan(const unsigned* __restrict__ hist, unsigned* cursor) {
    __shared__ unsigned partial[1024];
    int t = threadIdx.x;
    unsigned s = 0;
    for (int i = 0; i < 64; i++) s += hist[t * 64 + i];
    partial[t] = s;
    __syncthreads();
    for (int off = 1; off < 1024; off <<= 1) {
        unsigned v = (t >= off) ? partial[t - off] : 0u;
        __syncthreads();
        partial[t] += v;
        __syncthreads();
    }
    unsigned run = (t == 0) ? 0u : partial[t - 1];
    for (int i = 0; i < 64; i++) {
        cursor[t * 64 + i] = run;
        run += hist[t * 64 + i];
    }
}

// ---------------- K4: scatter keys into descending-value order (counting sort).
__global__ void k_scatter(const unsigned* __restrict__ counters,
                          const unsigned long long* __restrict__ keys,
                          unsigned* cursor, unsigned long long* sorted) {
    unsigned np = counters[1]; if (np > PEAK_CAP) np = PEAK_CAP;
    unsigned t = blockIdx.x * 256u + threadIdx.x;
    if (t < np) {
        unsigned long long key = keys[t];
        unsigned bits = (unsigned)(key >> 32);
        unsigned pos = atomicAdd(&cursor[(~bits) & 0xFFFFu], 1u);
        if (pos < PEAK_CAP) sorted[pos] = key;
    }
}

// ---------------- K5: fix ties — re-order each equal-value run by ascending voxel idx
// (matches lax.top_k tie-breaking).
__global__ void k_tiefix(const unsigned long long* __restrict__ sorted,
                         unsigned long long* outk) {
    unsigned t = blockIdx.x * 256u + threadIdx.x;
    if (t >= PEAK_CAP) return;
    unsigned long long key = sorted[t];
    unsigned bits = (unsigned)(key >> 32);
    if (bits == 0u) { outk[t] = 0ull; return; }
    unsigned s = t;
    while (s > 0 && (unsigned)(sorted[s - 1] >> 32) == bits) s--;
    unsigned myidx = (unsigned)key;
    unsigned rank = 0, e = s;
    while (e < PEAK_CAP) {
        unsigned long long k2 = sorted[e];
        if ((unsigned)(k2 >> 32) != bits) break;
        if ((unsigned)k2 < myidx) rank++;
        e++;
    }
    outk[s + rank] = key;
}

// ---------------- K6: centroid refinement + output. One wave per output row.
__global__ void k_out(const float* __restrict__ vol,
                      const unsigned long long* __restrict__ outk,
                      float4* __restrict__ out, float* __restrict__ valid) {
    unsigned gtid = blockIdx.x * 256u + threadIdx.x;
    unsigned row = gtid >> 6;
    int lane = threadIdx.x & 63;
    if (row >= KPEAKS) return;
    unsigned long long key = outk[row];
    unsigned bits = (unsigned)(key >> 32);
    unsigned idx = (unsigned)key;
    int z = idx >> 18, y = (idx >> 9) & 511, x = idx & 511;
    float s0 = 0.f, sx = 0.f, sy = 0.f, sz = 0.f;
    if (bits != 0u) {
        for (int p = lane; p < 343; p += 64) {
            int dz = p / 49; int r = p - dz * 49; int dy = r / 7; int dx = r - dy * 7;
            int nz = z + dz - 3, ny = y + dy - 3, nx = x + dx - 3;
            if ((unsigned)nz < DD && (unsigned)ny < HH && (unsigned)nx < WW) {
                float v = vol[((unsigned)nz << 18) + ((unsigned)ny << 9) + (unsigned)nx];
                s0 += v;
                sx += v * (float)(dx - 3);
                sy += v * (float)(dy - 3);
                sz += v * (float)(dz - 3);
            }
        }
    }
    for (int off = 32; off; off >>= 1) {
        s0 += __shfl_down(s0, off);
        sx += __shfl_down(sx, off);
        sy += __shfl_down(sy, off);
        sz += __shfl_down(sz, off);
    }
    if (lane == 0) {
        if (bits == 0u) {
            out[row] = make_float4(0.f, 0.f, 0.f, 0.f);
            valid[row] = 0.f;
        } else {
            float val = __uint_as_float(bits);
            float xloc = sx / s0, yloc = sy / s0, zloc = sz / s0;
            float xr = ((float)x + xloc - (float)(WW - 1) * 0.5f) * 0.1f;
            float yr = ((float)y + yloc - (float)(HH - 1) * 0.5f) * 0.1f;
            float zr = ((float)z + zloc + 0.5f) * 0.02f - 2.0f;
            out[row] = make_float4(xr, yr, zr, val);
            valid[row] = 1.f;
        }
    }
}

extern "C" void kernel_launch(void* const* d_in, const int* in_sizes, int n_in,
                              void* d_out, int out_size, void* d_ws, size_t ws_size,
                              hipStream_t stream) {
    const float* vol = (const float*)d_in[0];
    // d_in[1] = max_peaks scalar (device); fixed at 131072 for this problem.

    char* w = (char*)d_ws;
    unsigned* counters = (unsigned*)w;                                   // 256 B used
    unsigned* hist     = (unsigned*)(w + 1024);                          // 256 KB
    unsigned* cursor   = (unsigned*)(w + 1024 + NBINS * 4);              // 256 KB
    unsigned* cand     = (unsigned*)(w + 1024 + 2 * NBINS * 4);         // 2 MB
    unsigned long long* keys   = (unsigned long long*)(w + 1024 + 2 * NBINS * 4 + CAND_CAP * 4);
    unsigned long long* sorted = keys + PEAK_CAP;
    unsigned long long* keyout = sorted + PEAK_CAP;
    // total ~14.8 MB of ws

    float* out_rows = (float*)d_out;                 // (131072, 4)
    float* valid = out_rows + (size_t)KPEAKS * 4;    // (131072,)

    k_init<<<PEAK_CAP / 256, 256, 0, stream>>>(counters, hist, sorted);
    k_cand<<<NVOX / 4096, 256, 0, stream>>>((const float4*)vol, counters, cand);
    k_peak<<<2048, 256, 0, stream>>>(vol, counters, cand, hist, keys);
    k_scan<<<1, 1024, 0, stream>>>(hist, cursor);
    k_scatter<<<PEAK_CAP / 256, 256, 0, stream>>>(counters, keys, cursor, sorted);
    k_tiefix<<<PEAK_CAP / 256, 256, 0, stream>>>(sorted, keyout);
    k_out<<<(KPEAKS * 64) / 256, 256, 0, stream>>>(vol, keyout, (float4*)out_rows, valid);
}

// Round 2
// 380.533 us; speedup vs baseline: 1.2236x; 1.2236x over previous
//
#include <hip/hip_runtime.h>

#define DD 128
#define HH 512
#define WW 512
#define NVOX (DD*HH*WW)          // 33554432
#define THRESHV 0.997f
#define KPEAKS 131072
#define CAND_CAP (1u<<19)        // 524288 candidate slots (expect ~100K)
#define PEAK_CAP (1u<<18)        // 262144 peak slots (expect ~63K)
#define NBINS 65536

// peaks all lie in (0.997, 1.0): float bits in [0x3F7F3B65, 0x3F7FFFFF],
// upper 16 bits constant 0x3F7F -> low 16 bits monotone in value.
// bin = (~bits)&0xFFFF so ascending bin == descending value.

// ---------------- K0: init scratch (ws is poisoned 0xAA before every call)
__global__ void k_init(unsigned* counters, unsigned* hist, unsigned long long* sorted) {
    unsigned t = blockIdx.x * 256u + threadIdx.x;
    if (t < 64) counters[t] = 0u;
    if (t < NBINS) hist[t] = 0u;
    if (t < PEAK_CAP) sorted[t] = 0ull;
}

// ---------------- K1: stream volume, compact above-threshold candidates.
// 8192 blocks x 256 threads; 4096 voxels/block. All 4 float4 loads issued
// BEFORE any consumption so they stay in flight (R0 had VGPR=8, serialized).
__global__ void k_cand(const float4* __restrict__ vol4, unsigned* counters,
                       unsigned* __restrict__ cand) {
    __shared__ unsigned lcnt, lbase;
    __shared__ unsigned lbuf[512];   // E[candidates/block] ~= 12; 512 is >> max
    if (threadIdx.x == 0) lcnt = 0;
    __syncthreads();
    unsigned base4 = blockIdx.x * 1024u + threadIdx.x;   // float4 units
    float4 a = vol4[base4];
    float4 b = vol4[base4 + 256u];
    float4 c = vol4[base4 + 512u];
    float4 d = vol4[base4 + 768u];
    unsigned va = (base4) * 4u, vb = (base4 + 256u) * 4u,
             vc = (base4 + 512u) * 4u, vd = (base4 + 768u) * 4u;
    if (a.x > THRESHV) lbuf[atomicAdd(&lcnt, 1u) & 511u] = va;
    if (a.y > THRESHV) lbuf[atomicAdd(&lcnt, 1u) & 511u] = va + 1u;
    if (a.z > THRESHV) lbuf[atomicAdd(&lcnt, 1u) & 511u] = va + 2u;
    if (a.w > THRESHV) lbuf[atomicAdd(&lcnt, 1u) & 511u] = va + 3u;
    if (b.x > THRESHV) lbuf[atomicAdd(&lcnt, 1u) & 511u] = vb;
    if (b.y > THRESHV) lbuf[atomicAdd(&lcnt, 1u) & 511u] = vb + 1u;
    if (b.z > THRESHV) lbuf[atomicAdd(&lcnt, 1u) & 511u] = vb + 2u;
    if (b.w > THRESHV) lbuf[atomicAdd(&lcnt, 1u) & 511u] = vb + 3u;
    if (c.x > THRESHV) lbuf[atomicAdd(&lcnt, 1u) & 511u] = vc;
    if (c.y > THRESHV) lbuf[atomicAdd(&lcnt, 1u) & 511u] = vc + 1u;
    if (c.z > THRESHV) lbuf[atomicAdd(&lcnt, 1u) & 511u] = vc + 2u;
    if (c.w > THRESHV) lbuf[atomicAdd(&lcnt, 1u) & 511u] = vc + 3u;
    if (d.x > THRESHV) lbuf[atomicAdd(&lcnt, 1u) & 511u] = vd;
    if (d.y > THRESHV) lbuf[atomicAdd(&lcnt, 1u) & 511u] = vd + 1u;
    if (d.z > THRESHV) lbuf[atomicAdd(&lcnt, 1u) & 511u] = vd + 2u;
    if (d.w > THRESHV) lbuf[atomicAdd(&lcnt, 1u) & 511u] = vd + 3u;
    __syncthreads();
    if (threadIdx.x == 0) lbase = atomicAdd(&counters[0], lcnt);
    __syncthreads();
    unsigned n = lcnt > 512u ? 512u : lcnt;
    for (unsigned i = threadIdx.x; i < n; i += 256u) {
        unsigned p = lbase + i;
        if (p < CAND_CAP) cand[p] = lbuf[i];
    }
}

// ---------------- K2: verify peaks (wave per candidate) AND compute centroid
// sums in the same pass (values are already loaded). Emits key + float4 sums.
// Slot index == position in keys[]/psums[].
__global__ void k_peak(const float* __restrict__ vol, unsigned* counters,
                       const unsigned* __restrict__ cand, unsigned* hist,
                       unsigned long long* keys, float4* psums) {
    __shared__ unsigned lcnt, lbase;
    __shared__ unsigned long long lbuf[256];
    __shared__ float4 sbuf[256];
    if (threadIdx.x == 0) lcnt = 0;
    __syncthreads();
    unsigned nc = counters[0]; if (nc > CAND_CAP) nc = CAND_CAP;
    int lane = threadIdx.x & 63;
    unsigned wv = (blockIdx.x * blockDim.x + threadIdx.x) >> 6;
    unsigned nw = (gridDim.x * blockDim.x) >> 6;
    for (unsigned ci = wv; ci < nc; ci += nw) {
        unsigned idx = cand[ci];
        int z = idx >> 18, y = (idx >> 9) & 511, x = idx & 511;
        float center = vol[idx];
        bool kill = false;
        float s0 = 0.f, sx = 0.f, sy = 0.f, sz = 0.f;
        for (int p = lane; p < 343; p += 64) {
            int dz = p / 49; int r = p - dz * 49; int dy = r / 7; int dx = r - dy * 7;
            int nz = z + dz - 3, ny = y + dy - 3, nx = x + dx - 3;
            if ((unsigned)nz < DD && (unsigned)ny < HH && (unsigned)nx < WW) {
                float v = vol[((unsigned)nz << 18) + ((unsigned)ny << 9) + (unsigned)nx];
                if (v > center) kill = true;
                s0 += v;
                sx += v * (float)(dx - 3);
                sy += v * (float)(dy - 3);
                sz += v * (float)(dz - 3);
            }
        }
        bool killed = __any(kill);
        if (!killed) {
            for (int off = 32; off; off >>= 1) {
                s0 += __shfl_down(s0, off);
                sx += __shfl_down(sx, off);
                sy += __shfl_down(sy, off);
                sz += __shfl_down(sz, off);
            }
            if (lane == 0) {
                unsigned bits = __float_as_uint(center);
                atomicAdd(&hist[(~bits) & 0xFFFFu], 1u);
                unsigned li = atomicAdd(&lcnt, 1u);
                if (li < 256u) {
                    lbuf[li] = ((unsigned long long)bits << 32) | idx;
                    sbuf[li] = make_float4(s0, sx, sy, sz);
                }
            }
        }
    }
    __syncthreads();
    if (threadIdx.x == 0) lbase = atomicAdd(&counters[1], lcnt);
    __syncthreads();
    unsigned n = lcnt > 256u ? 256u : lcnt;
    for (unsigned i = threadIdx.x; i < n; i += 256u) {
        unsigned p = lbase + i;
        if (p < PEAK_CAP) { keys[p] = lbuf[i]; psums[p] = sbuf[i]; }
    }
}

// ---------------- K3: exclusive prefix sum over 65536 bins (single block).
__global__ void k_scan(const unsigned* __restrict__ hist, unsigned* cursor) {
    __shared__ unsigned partial[1024];
    int t = threadIdx.x;
    unsigned s = 0;
    for (int i = 0; i < 64; i++) s += hist[t * 64 + i];
    partial[t] = s;
    __syncthreads();
    for (int off = 1; off < 1024; off <<= 1) {
        unsigned v = (t >= off) ? partial[t - off] : 0u;
        __syncthreads();
        partial[t] += v;
        __syncthreads();
    }
    unsigned run = (t == 0) ? 0u : partial[t - 1];
    for (int i = 0; i < 64; i++) {
        cursor[t * 64 + i] = run;
        run += hist[t * 64 + i];
    }
}

// ---------------- K4: scatter keys (+slot payload) into descending-value order.
__global__ void k_scatter(const unsigned* __restrict__ counters,
                          const unsigned long long* __restrict__ keys,
                          unsigned* cursor, unsigned long long* sorted,
                          unsigned* sslot) {
    unsigned np = counters[1]; if (np > PEAK_CAP) np = PEAK_CAP;
    unsigned t = blockIdx.x * 256u + threadIdx.x;
    if (t < np) {
        unsigned long long key = keys[t];
        unsigned bits = (unsigned)(key >> 32);
        unsigned pos = atomicAdd(&cursor[(~bits) & 0xFFFFu], 1u);
        if (pos < PEAK_CAP) { sorted[pos] = key; sslot[pos] = t; }
    }
}

// ---------------- K5: fix ties — re-order each equal-value run by ascending
// voxel idx (lax.top_k tie-breaking). Slot payload follows.
__global__ void k_tiefix(const unsigned long long* __restrict__ sorted,
                         const unsigned* __restrict__ sslot,
                         unsigned long long* outk, unsigned* oslot) {
    unsigned t = blockIdx.x * 256u + threadIdx.x;
    if (t >= PEAK_CAP) return;
    unsigned long long key = sorted[t];
    unsigned bits = (unsigned)(key >> 32);
    if (bits == 0u) { outk[t] = 0ull; return; }
    unsigned s = t;
    while (s > 0 && (unsigned)(sorted[s - 1] >> 32) == bits) s--;
    unsigned myidx = (unsigned)key;
    unsigned rank = 0, e = s;
    while (e < PEAK_CAP) {
        unsigned long long k2 = sorted[e];
        if ((unsigned)(k2 >> 32) != bits) break;
        if ((unsigned)k2 < myidx) rank++;
        e++;
    }
    outk[s + rank] = key;
    oslot[s + rank] = sslot[t];
}

// ---------------- K6: output. One THREAD per row; sums are precomputed.
__global__ void k_out(const unsigned long long* __restrict__ outk,
                      const unsigned* __restrict__ oslot,
                      const float4* __restrict__ psums,
                      float4* __restrict__ out, float* __restrict__ valid) {
    unsigned row = blockIdx.x * 256u + threadIdx.x;
    if (row >= KPEAKS) return;
    unsigned long long key = outk[row];
    unsigned bits = (unsigned)(key >> 32);
    if (bits == 0u) {
        out[row] = make_float4(0.f, 0.f, 0.f, 0.f);
        valid[row] = 0.f;
        return;
    }
    unsigned idx = (unsigned)key;
    int z = idx >> 18, y = (idx >> 9) & 511, x = idx & 511;
    float4 s = psums[oslot[row]];
    float val = __uint_as_float(bits);
    float xloc = s.y / s.x, yloc = s.z / s.x, zloc = s.w / s.x;
    float xr = ((float)x + xloc - (float)(WW - 1) * 0.5f) * 0.1f;
    float yr = ((float)y + yloc - (float)(HH - 1) * 0.5f) * 0.1f;
    float zr = ((float)z + zloc + 0.5f) * 0.02f - 2.0f;
    out[row] = make_float4(xr, yr, zr, val);
    valid[row] = 1.f;
}

extern "C" void kernel_launch(void* const* d_in, const int* in_sizes, int n_in,
                              void* d_out, int out_size, void* d_ws, size_t ws_size,
                              hipStream_t stream) {
    const float* vol = (const float*)d_in[0];
    // d_in[1] = max_peaks scalar (device); fixed at 131072 for this problem.

    char* w = (char*)d_ws;
    unsigned* counters = (unsigned*)w;                                   // 1 KB
    unsigned* hist     = (unsigned*)(w + 1024);                          // 256 KB
    unsigned* cursor   = (unsigned*)(w + 1024 + NBINS * 4);              // 256 KB
    unsigned* cand     = (unsigned*)(w + 1024 + 2 * NBINS * 4);          // 2 MB
    char* w2 = w + 1024 + 2 * NBINS * 4 + CAND_CAP * 4;
    unsigned long long* keys   = (unsigned long long*)w2;                // 2 MB
    unsigned long long* sorted = keys + PEAK_CAP;                        // 2 MB
    unsigned long long* keyout = sorted + PEAK_CAP;                      // 2 MB
    unsigned* sslot = (unsigned*)(keyout + PEAK_CAP);                    // 1 MB
    unsigned* oslot = sslot + PEAK_CAP;                                  // 1 MB
    float4*   psums = (float4*)(oslot + PEAK_CAP);                       // 4 MB
    // total ~14.5 MB of ws

    float* out_rows = (float*)d_out;                 // (131072, 4)
    float* valid = out_rows + (size_t)KPEAKS * 4;    // (131072,)

    k_init<<<PEAK_CAP / 256, 256, 0, stream>>>(counters, hist, sorted);
    k_cand<<<NVOX / 4096, 256, 0, stream>>>((const float4*)vol, counters, cand);
    k_peak<<<2048, 256, 0, stream>>>(vol, counters, cand, hist, keys, psums);
    k_scan<<<1, 1024, 0, stream>>>(hist, cursor);
    k_scatter<<<PEAK_CAP / 256, 256, 0, stream>>>(counters, keys, cursor, sorted, sslot);
    k_tiefix<<<PEAK_CAP / 256, 256, 0, stream>>>(sorted, sslot, keyout, oslot);
    k_out<<<(KPEAKS + 255) / 256, 256, 0, stream>>>(keyout, oslot, psums, (float4*)out_rows, valid);
}

// Round 3
// 332.049 us; speedup vs baseline: 1.4022x; 1.1460x over previous
//
#include <hip/hip_runtime.h>

#define DD 128
#define HH 512
#define WW 512
#define NVOX (DD*HH*WW)          // 33554432
#define THRESHV 0.997f
#define KPEAKS 131072
#define CAND_CAP (1u<<19)        // 524288 candidate slots (expect ~100K)
#define PEAK_CAP (1u<<18)        // 262144 peak slots (expect ~63K)
#define NBINS 65536

// peaks all lie in (0.997, 1.0): float bits in [0x3F7F3B65, 0x3F7FFFFF],
// upper 16 bits constant 0x3F7F -> low 16 bits monotone in value.
// bin = (~bits)&0xFFFF so ascending bin == descending value.

// ---------------- K0: init scratch (ws is poisoned 0xAA before every call)
__global__ void k_init(unsigned* counters, unsigned* hist, unsigned long long* sorted) {
    unsigned t = blockIdx.x * 256u + threadIdx.x;
    if (t < 64) counters[t] = 0u;
    if (t < NBINS) hist[t] = 0u;
    if (t < PEAK_CAP) sorted[t] = 0ull;
}

// ---------------- K1: stream volume, compact above-threshold candidates.
// 4096 blocks x 256 threads; 8192 voxels/block (8 float4/thread).
// Loads are consumed ONLY by branchless mask ALU so the compiler can keep
// all 8 in flight (R2 had branchy LDS atomics between loads -> VGPR=16,
// serialized, 1.3 TB/s).
__global__ void k_cand(const float4* __restrict__ vol4, unsigned* counters,
                       unsigned* __restrict__ cand) {
    __shared__ unsigned lcnt, lbase;
    __shared__ unsigned lbuf[512];   // E[cands/block] ~= 25; 512 >> max
    if (threadIdx.x == 0) lcnt = 0;
    __syncthreads();
    unsigned base4 = blockIdx.x * 2048u + threadIdx.x;   // float4 units
    float4 v[8];
#pragma unroll
    for (int i = 0; i < 8; i++) v[i] = vol4[base4 + i * 256u];
    unsigned m = 0u;
#pragma unroll
    for (int i = 0; i < 8; i++) {
        m |= (v[i].x > THRESHV ? 1u : 0u) << (4 * i);
        m |= (v[i].y > THRESHV ? 1u : 0u) << (4 * i + 1);
        m |= (v[i].z > THRESHV ? 1u : 0u) << (4 * i + 2);
        m |= (v[i].w > THRESHV ? 1u : 0u) << (4 * i + 3);
    }
    while (m) {
        int b = __ffs(m) - 1;
        m &= m - 1u;
        unsigned f4 = base4 + (unsigned)(b >> 2) * 256u;
        lbuf[atomicAdd(&lcnt, 1u) & 511u] = f4 * 4u + (unsigned)(b & 3);
    }
    __syncthreads();
    if (threadIdx.x == 0) lbase = atomicAdd(&counters[0], lcnt);
    __syncthreads();
    unsigned n = lcnt > 512u ? 512u : lcnt;
    for (unsigned i = threadIdx.x; i < n; i += 256u) {
        unsigned p = lbase + i;
        if (p < CAND_CAP) cand[p] = lbuf[i];
    }
}

// ---------------- K2: verify peaks + centroid sums, wave per candidate.
// lane l<49 owns row (dz=l/7, dy=l%7); row = 7 contiguous floats loaded as
// two dwordx4 (4B-aligned). x-edge candidates (~1.2%) take a wave-uniform
// scalar fallback. Kill-check and sums share the same loaded values.
__global__ void k_peak(const float* __restrict__ vol, unsigned* counters,
                       const unsigned* __restrict__ cand, unsigned* hist,
                       unsigned long long* keys, float4* psums) {
    __shared__ unsigned lcnt, lbase;
    __shared__ unsigned long long lbuf[256];
    __shared__ float4 sbuf[256];
    if (threadIdx.x == 0) lcnt = 0;
    __syncthreads();
    unsigned nc = counters[0]; if (nc > CAND_CAP) nc = CAND_CAP;
    int lane = threadIdx.x & 63;
    int dz = lane / 7, dy = lane - dz * 7;    // meaningful for lane<49
    unsigned wv = (blockIdx.x * blockDim.x + threadIdx.x) >> 6;
    unsigned nw = (gridDim.x * blockDim.x) >> 6;
    for (unsigned ci = wv; ci < nc; ci += nw) {
        unsigned idx = cand[ci];
        int z = idx >> 18, y = (idx >> 9) & 511, x = idx & 511;
        float center = vol[idx];
        int nz = z + dz - 3, ny = y + dy - 3;
        bool rowok = (lane < 49) && ((unsigned)nz < DD) && ((unsigned)ny < HH);
        size_t rowbase = rowok ? (((size_t)(unsigned)nz << 18) | ((size_t)(unsigned)ny << 9))
                               : (((size_t)z << 18) | ((size_t)y << 9));
        float rv[7];
        if (x >= 3 && x <= WW - 4) {
            // interior x: rows are [x-3, x+3]; two aligned-enough dwordx4 loads
            float4 f0 = *(const float4*)(vol + rowbase + (unsigned)(x - 3));
            float4 f1 = *(const float4*)(vol + rowbase + (unsigned)(x + 1));
            rv[0] = f0.x; rv[1] = f0.y; rv[2] = f0.z; rv[3] = f0.w;
            rv[4] = f1.x; rv[5] = f1.y; rv[6] = f1.z;
        } else {
            // x edge (wave-uniform branch): scalar with clamped addresses
#pragma unroll
            for (int d = 0; d < 7; d++) {
                int nx = x + d - 3;
                bool ok = (unsigned)nx < WW;
                float vv = vol[rowbase + (unsigned)(ok ? nx : x)];
                rv[d] = ok ? vv : 0.f;
            }
        }
        if (!rowok) {
#pragma unroll
            for (int d = 0; d < 7; d++) rv[d] = 0.f;
        }
        bool kill = false;
        float s0r = 0.f, sxr = 0.f;
#pragma unroll
        for (int d = 0; d < 7; d++) {
            kill |= rv[d] > center;
            s0r += rv[d];
            sxr += rv[d] * (float)(d - 3);
        }
        if (!__any(kill)) {
            float s0 = s0r, sx = sxr;
            float sy = s0r * (float)(dy - 3);
            float sz = s0r * (float)(dz - 3);
            for (int off = 32; off; off >>= 1) {
                s0 += __shfl_down(s0, off);
                sx += __shfl_down(sx, off);
                sy += __shfl_down(sy, off);
                sz += __shfl_down(sz, off);
            }
            if (lane == 0) {
                unsigned bits = __float_as_uint(center);
                atomicAdd(&hist[(~bits) & 0xFFFFu], 1u);
                unsigned li = atomicAdd(&lcnt, 1u);
                if (li < 256u) {
                    lbuf[li] = ((unsigned long long)bits << 32) | idx;
                    sbuf[li] = make_float4(s0, sx, sy, sz);
                }
            }
        }
    }
    __syncthreads();
    if (threadIdx.x == 0) lbase = atomicAdd(&counters[1], lcnt);
    __syncthreads();
    unsigned n = lcnt > 256u ? 256u : lcnt;
    for (unsigned i = threadIdx.x; i < n; i += 256u) {
        unsigned p = lbase + i;
        if (p < PEAK_CAP) { keys[p] = lbuf[i]; psums[p] = sbuf[i]; }
    }
}

// ---------------- K3: exclusive prefix sum over 65536 bins (single block),
// uint4-vectorized loads/stores.
__global__ void k_scan(const unsigned* __restrict__ hist, unsigned* cursor) {
    __shared__ unsigned partial[1024];
    int t = threadIdx.x;
    const uint4* h4 = (const uint4*)(hist + t * 64);
    uint4 loc[16];
#pragma unroll
    for (int i = 0; i < 16; i++) loc[i] = h4[i];
    unsigned s = 0;
#pragma unroll
    for (int i = 0; i < 16; i++) s += loc[i].x + loc[i].y + loc[i].z + loc[i].w;
    partial[t] = s;
    __syncthreads();
    for (int off = 1; off < 1024; off <<= 1) {
        unsigned v = (t >= off) ? partial[t - off] : 0u;
        __syncthreads();
        partial[t] += v;
        __syncthreads();
    }
    unsigned run = (t == 0) ? 0u : partial[t - 1];
    uint4* c4 = (uint4*)(cursor + t * 64);
#pragma unroll
    for (int i = 0; i < 16; i++) {
        uint4 h = loc[i]; uint4 o;
        o.x = run; run += h.x;
        o.y = run; run += h.y;
        o.z = run; run += h.z;
        o.w = run; run += h.w;
        c4[i] = o;
    }
}

// ---------------- K4: scatter keys (+slot payload) into descending-value order.
__global__ void k_scatter(const unsigned* __restrict__ counters,
                          const unsigned long long* __restrict__ keys,
                          unsigned* cursor, unsigned long long* sorted,
                          unsigned* sslot) {
    unsigned np = counters[1]; if (np > PEAK_CAP) np = PEAK_CAP;
    unsigned t = blockIdx.x * 256u + threadIdx.x;
    if (t < np) {
        unsigned long long key = keys[t];
        unsigned bits = (unsigned)(key >> 32);
        unsigned pos = atomicAdd(&cursor[(~bits) & 0xFFFFu], 1u);
        if (pos < PEAK_CAP) { sorted[pos] = key; sslot[pos] = t; }
    }
}

// ---------------- K5: fix ties — re-order each equal-value run by ascending
// voxel idx (lax.top_k tie-breaking). Slot payload follows.
__global__ void k_tiefix(const unsigned long long* __restrict__ sorted,
                         const unsigned* __restrict__ sslot,
                         unsigned long long* outk, unsigned* oslot) {
    unsigned t = blockIdx.x * 256u + threadIdx.x;
    if (t >= PEAK_CAP) return;
    unsigned long long key = sorted[t];
    unsigned bits = (unsigned)(key >> 32);
    if (bits == 0u) { outk[t] = 0ull; return; }
    unsigned s = t;
    while (s > 0 && (unsigned)(sorted[s - 1] >> 32) == bits) s--;
    unsigned myidx = (unsigned)key;
    unsigned rank = 0, e = s;
    while (e < PEAK_CAP) {
        unsigned long long k2 = sorted[e];
        if ((unsigned)(k2 >> 32) != bits) break;
        if ((unsigned)k2 < myidx) rank++;
        e++;
    }
    outk[s + rank] = key;
    oslot[s + rank] = sslot[t];
}

// ---------------- K6: output. One THREAD per row; sums are precomputed.
__global__ void k_out(const unsigned long long* __restrict__ outk,
                      const unsigned* __restrict__ oslot,
                      const float4* __restrict__ psums,
                      float4* __restrict__ out, float* __restrict__ valid) {
    unsigned row = blockIdx.x * 256u + threadIdx.x;
    if (row >= KPEAKS) return;
    unsigned long long key = outk[row];
    unsigned bits = (unsigned)(key >> 32);
    if (bits == 0u) {
        out[row] = make_float4(0.f, 0.f, 0.f, 0.f);
        valid[row] = 0.f;
        return;
    }
    unsigned idx = (unsigned)key;
    int z = idx >> 18, y = (idx >> 9) & 511, x = idx & 511;
    float4 s = psums[oslot[row]];
    float val = __uint_as_float(bits);
    float xloc = s.y / s.x, yloc = s.z / s.x, zloc = s.w / s.x;
    float xr = ((float)x + xloc - (float)(WW - 1) * 0.5f) * 0.1f;
    float yr = ((float)y + yloc - (float)(HH - 1) * 0.5f) * 0.1f;
    float zr = ((float)z + zloc + 0.5f) * 0.02f - 2.0f;
    out[row] = make_float4(xr, yr, zr, val);
    valid[row] = 1.f;
}

extern "C" void kernel_launch(void* const* d_in, const int* in_sizes, int n_in,
                              void* d_out, int out_size, void* d_ws, size_t ws_size,
                              hipStream_t stream) {
    const float* vol = (const float*)d_in[0];
    // d_in[1] = max_peaks scalar (device); fixed at 131072 for this problem.

    char* w = (char*)d_ws;
    unsigned* counters = (unsigned*)w;                                   // 1 KB
    unsigned* hist     = (unsigned*)(w + 1024);                          // 256 KB
    unsigned* cursor   = (unsigned*)(w + 1024 + NBINS * 4);              // 256 KB
    unsigned* cand     = (unsigned*)(w + 1024 + 2 * NBINS * 4);          // 2 MB
    char* w2 = w + 1024 + 2 * NBINS * 4 + CAND_CAP * 4;
    unsigned long long* keys   = (unsigned long long*)w2;                // 2 MB
    unsigned long long* sorted = keys + PEAK_CAP;                        // 2 MB
    unsigned long long* keyout = sorted + PEAK_CAP;                      // 2 MB
    unsigned* sslot = (unsigned*)(keyout + PEAK_CAP);                    // 1 MB
    unsigned* oslot = sslot + PEAK_CAP;                                  // 1 MB
    float4*   psums = (float4*)(oslot + PEAK_CAP);                       // 4 MB
    // total ~14.5 MB of ws

    float* out_rows = (float*)d_out;                 // (131072, 4)
    float* valid = out_rows + (size_t)KPEAKS * 4;    // (131072,)

    k_init<<<PEAK_CAP / 256, 256, 0, stream>>>(counters, hist, sorted);
    k_cand<<<NVOX / 8192, 256, 0, stream>>>((const float4*)vol, counters, cand);
    k_peak<<<4096, 256, 0, stream>>>(vol, counters, cand, hist, keys, psums);
    k_scan<<<1, 1024, 0, stream>>>(hist, cursor);
    k_scatter<<<PEAK_CAP / 256, 256, 0, stream>>>(counters, keys, cursor, sorted, sslot);
    k_tiefix<<<PEAK_CAP / 256, 256, 0, stream>>>(sorted, sslot, keyout, oslot);
    k_out<<<(KPEAKS + 255) / 256, 256, 0, stream>>>(keyout, oslot, psums, (float4*)out_rows, valid);
}

// Round 4
// 261.169 us; speedup vs baseline: 1.7828x; 1.2714x over previous
//
#include <hip/hip_runtime.h>

#define DD 128
#define HH 512
#define WW 512
#define NVOX (DD*HH*WW)          // 33554432
#define THRESHV 0.997f
#define KPEAKS 131072
#define PEAK_CAP (1u<<18)        // 262144 peak slots (expect ~63K)
#define NBINS 65536

// peaks all lie in (0.997, 1.0): float bits in [0x3F7F3B65, 0x3F7FFFFF],
// upper 16 bits constant 0x3F7F -> low 16 bits monotone in value.
// bin = (~bits)&0xFFFF so ascending bin == descending value.

// ---------------- K0: init scratch (ws is poisoned 0xAA before every call)
__global__ void k_init(unsigned* counters, unsigned* hist, unsigned long long* sorted) {
    unsigned t = blockIdx.x * 256u + threadIdx.x;
    if (t < 64) counters[t] = 0u;
    if (t < NBINS) hist[t] = 0u;
    if (t < PEAK_CAP) sorted[t] = 0ull;
}

// ---------------- K1: FUSED stream + verify + centroid.
// Phase A: block streams 8192 voxels (8 float4/thread), candidates -> LDS.
// Phase B: block's 4 waves verify LDS candidates (wave per candidate):
//   lane l<49 owns row (dz=l/7, dy=l%7) = 7 contiguous floats via 2 dwordx4;
//   kill-check + centroid sums from the same loaded values; emit key+sums.
__global__ void k_find(const float4* __restrict__ vol4, const float* __restrict__ vol,
                       unsigned* counters, unsigned* hist,
                       unsigned long long* keys, float4* psums) {
    __shared__ unsigned lcnt, pcnt, lbase;
    __shared__ unsigned cidx[512];            // candidate voxel indices
    __shared__ unsigned long long lbuf[256];  // surviving peak keys
    __shared__ float4 sbuf[256];              // surviving peak centroid sums
    if (threadIdx.x == 0) { lcnt = 0; pcnt = 0; }
    __syncthreads();

    // ---- Phase A: stream
    unsigned base4 = blockIdx.x * 2048u + threadIdx.x;   // float4 units
    float4 v[8];
#pragma unroll
    for (int i = 0; i < 8; i++) v[i] = vol4[base4 + i * 256u];
    unsigned m = 0u;
#pragma unroll
    for (int i = 0; i < 8; i++) {
        m |= (v[i].x > THRESHV ? 1u : 0u) << (4 * i);
        m |= (v[i].y > THRESHV ? 1u : 0u) << (4 * i + 1);
        m |= (v[i].z > THRESHV ? 1u : 0u) << (4 * i + 2);
        m |= (v[i].w > THRESHV ? 1u : 0u) << (4 * i + 3);
    }
    while (m) {
        int b = __ffs(m) - 1;
        m &= m - 1u;
        unsigned f4 = base4 + (unsigned)(b >> 2) * 256u;
        cidx[atomicAdd(&lcnt, 1u) & 511u] = f4 * 4u + (unsigned)(b & 3);
    }
    __syncthreads();

    // ---- Phase B: verify (wave per candidate)
    unsigned n = lcnt > 512u ? 512u : lcnt;
    int lane = threadIdx.x & 63;
    int wv = threadIdx.x >> 6;                 // 0..3
    int dz = lane / 7, dy = lane - dz * 7;     // meaningful for lane<49
    for (unsigned ci = (unsigned)wv; ci < n; ci += 4u) {
        unsigned idx = cidx[ci];
        int z = idx >> 18, y = (idx >> 9) & 511, x = idx & 511;
        float center = vol[idx];               // line is L1/L2-hot (we streamed it)
        int nz = z + dz - 3, ny = y + dy - 3;
        bool rowok = (lane < 49) && ((unsigned)nz < DD) && ((unsigned)ny < HH);
        size_t rowbase = rowok ? (((size_t)(unsigned)nz << 18) | ((size_t)(unsigned)ny << 9))
                               : (((size_t)z << 18) | ((size_t)y << 9));
        float rv[7];
        if (x >= 3 && x <= WW - 4) {
            float4 f0 = *(const float4*)(vol + rowbase + (unsigned)(x - 3));
            float4 f1 = *(const float4*)(vol + rowbase + (unsigned)(x + 1));
            rv[0] = f0.x; rv[1] = f0.y; rv[2] = f0.z; rv[3] = f0.w;
            rv[4] = f1.x; rv[5] = f1.y; rv[6] = f1.z;
        } else {
            // x edge (wave-uniform branch): scalar with clamped addresses
#pragma unroll
            for (int d = 0; d < 7; d++) {
                int nx = x + d - 3;
                bool ok = (unsigned)nx < WW;
                float vv = vol[rowbase + (unsigned)(ok ? nx : x)];
                rv[d] = ok ? vv : 0.f;
            }
        }
        if (!rowok) {
#pragma unroll
            for (int d = 0; d < 7; d++) rv[d] = 0.f;
        }
        bool kill = false;
        float s0r = 0.f, sxr = 0.f;
#pragma unroll
        for (int d = 0; d < 7; d++) {
            kill |= rv[d] > center;
            s0r += rv[d];
            sxr += rv[d] * (float)(d - 3);
        }
        if (!__any(kill)) {
            float s0 = s0r, sx = sxr;
            float sy = s0r * (float)(dy - 3);
            float sz = s0r * (float)(dz - 3);
            for (int off = 32; off; off >>= 1) {
                s0 += __shfl_down(s0, off);
                sx += __shfl_down(sx, off);
                sy += __shfl_down(sy, off);
                sz += __shfl_down(sz, off);
            }
            if (lane == 0) {
                unsigned bits = __float_as_uint(center);
                atomicAdd(&hist[(~bits) & 0xFFFFu], 1u);
                unsigned li = atomicAdd(&pcnt, 1u);
                if (li < 256u) {
                    lbuf[li] = ((unsigned long long)bits << 32) | idx;
                    sbuf[li] = make_float4(s0, sx, sy, sz);
                }
            }
        }
    }
    __syncthreads();
    if (threadIdx.x == 0) lbase = atomicAdd(&counters[1], pcnt);
    __syncthreads();
    unsigned np = pcnt > 256u ? 256u : pcnt;
    for (unsigned i = threadIdx.x; i < np; i += 256u) {
        unsigned p = lbase + i;
        if (p < PEAK_CAP) { keys[p] = lbuf[i]; psums[p] = sbuf[i]; }
    }
}

// ---------------- K3: exclusive prefix sum over 65536 bins (single block),
// uint4-vectorized loads/stores.
__global__ void k_scan(const unsigned* __restrict__ hist, unsigned* cursor) {
    __shared__ unsigned partial[1024];
    int t = threadIdx.x;
    const uint4* h4 = (const uint4*)(hist + t * 64);
    uint4 loc[16];
#pragma unroll
    for (int i = 0; i < 16; i++) loc[i] = h4[i];
    unsigned s = 0;
#pragma unroll
    for (int i = 0; i < 16; i++) s += loc[i].x + loc[i].y + loc[i].z + loc[i].w;
    partial[t] = s;
    __syncthreads();
    for (int off = 1; off < 1024; off <<= 1) {
        unsigned v = (t >= off) ? partial[t - off] : 0u;
        __syncthreads();
        partial[t] += v;
        __syncthreads();
    }
    unsigned run = (t == 0) ? 0u : partial[t - 1];
    uint4* c4 = (uint4*)(cursor + t * 64);
#pragma unroll
    for (int i = 0; i < 16; i++) {
        uint4 h = loc[i]; uint4 o;
        o.x = run; run += h.x;
        o.y = run; run += h.y;
        o.z = run; run += h.z;
        o.w = run; run += h.w;
        c4[i] = o;
    }
}

// ---------------- K4: scatter keys (+slot payload) into descending-value order.
__global__ void k_scatter(const unsigned* __restrict__ counters,
                          const unsigned long long* __restrict__ keys,
                          unsigned* cursor, unsigned long long* sorted,
                          unsigned* sslot) {
    unsigned np = counters[1]; if (np > PEAK_CAP) np = PEAK_CAP;
    unsigned t = blockIdx.x * 256u + threadIdx.x;
    if (t < np) {
        unsigned long long key = keys[t];
        unsigned bits = (unsigned)(key >> 32);
        unsigned pos = atomicAdd(&cursor[(~bits) & 0xFFFFu], 1u);
        if (pos < PEAK_CAP) { sorted[pos] = key; sslot[pos] = t; }
    }
}

// ---------------- K5: fix ties — re-order each equal-value run by ascending
// voxel idx (lax.top_k tie-breaking). Slot payload follows.
__global__ void k_tiefix(const unsigned long long* __restrict__ sorted,
                         const unsigned* __restrict__ sslot,
                         unsigned long long* outk, unsigned* oslot) {
    unsigned t = blockIdx.x * 256u + threadIdx.x;
    if (t >= PEAK_CAP) return;
    unsigned long long key = sorted[t];
    unsigned bits = (unsigned)(key >> 32);
    if (bits == 0u) { outk[t] = 0ull; return; }
    unsigned s = t;
    while (s > 0 && (unsigned)(sorted[s - 1] >> 32) == bits) s--;
    unsigned myidx = (unsigned)key;
    unsigned rank = 0, e = s;
    while (e < PEAK_CAP) {
        unsigned long long k2 = sorted[e];
        if ((unsigned)(k2 >> 32) != bits) break;
        if ((unsigned)k2 < myidx) rank++;
        e++;
    }
    outk[s + rank] = key;
    oslot[s + rank] = sslot[t];
}

// ---------------- K6: output. One THREAD per row; sums are precomputed.
__global__ void k_out(const unsigned long long* __restrict__ outk,
                      const unsigned* __restrict__ oslot,
                      const float4* __restrict__ psums,
                      float4* __restrict__ out, float* __restrict__ valid) {
    unsigned row = blockIdx.x * 256u + threadIdx.x;
    if (row >= KPEAKS) return;
    unsigned long long key = outk[row];
    unsigned bits = (unsigned)(key >> 32);
    if (bits == 0u) {
        out[row] = make_float4(0.f, 0.f, 0.f, 0.f);
        valid[row] = 0.f;
        return;
    }
    unsigned idx = (unsigned)key;
    int z = idx >> 18, y = (idx >> 9) & 511, x = idx & 511;
    float4 s = psums[oslot[row]];
    float val = __uint_as_float(bits);
    float xloc = s.y / s.x, yloc = s.z / s.x, zloc = s.w / s.x;
    float xr = ((float)x + xloc - (float)(WW - 1) * 0.5f) * 0.1f;
    float yr = ((float)y + yloc - (float)(HH - 1) * 0.5f) * 0.1f;
    float zr = ((float)z + zloc + 0.5f) * 0.02f - 2.0f;
    out[row] = make_float4(xr, yr, zr, val);
    valid[row] = 1.f;
}

extern "C" void kernel_launch(void* const* d_in, const int* in_sizes, int n_in,
                              void* d_out, int out_size, void* d_ws, size_t ws_size,
                              hipStream_t stream) {
    const float* vol = (const float*)d_in[0];
    // d_in[1] = max_peaks scalar (device); fixed at 131072 for this problem.

    char* w = (char*)d_ws;
    unsigned* counters = (unsigned*)w;                                   // 1 KB
    unsigned* hist     = (unsigned*)(w + 1024);                          // 256 KB
    unsigned* cursor   = (unsigned*)(w + 1024 + NBINS * 4);              // 256 KB
    char* w2 = w + 1024 + 2 * NBINS * 4;
    unsigned long long* keys   = (unsigned long long*)w2;                // 2 MB
    unsigned long long* sorted = keys + PEAK_CAP;                        // 2 MB
    unsigned long long* keyout = sorted + PEAK_CAP;                      // 2 MB
    unsigned* sslot = (unsigned*)(keyout + PEAK_CAP);                    // 1 MB
    unsigned* oslot = sslot + PEAK_CAP;                                  // 1 MB
    float4*   psums = (float4*)(oslot + PEAK_CAP);                       // 4 MB
    // total ~12.5 MB of ws

    float* out_rows = (float*)d_out;                 // (131072, 4)
    float* valid = out_rows + (size_t)KPEAKS * 4;    // (131072,)

    k_init<<<PEAK_CAP / 256, 256, 0, stream>>>(counters, hist, sorted);
    k_find<<<NVOX / 8192, 256, 0, stream>>>((const float4*)vol, vol, counters, hist, keys, psums);
    k_scan<<<1, 1024, 0, stream>>>(hist, cursor);
    k_scatter<<<PEAK_CAP / 256, 256, 0, stream>>>(counters, keys, cursor, sorted, sslot);
    k_tiefix<<<PEAK_CAP / 256, 256, 0, stream>>>(sorted, sslot, keyout, oslot);
    k_out<<<(KPEAKS + 255) / 256, 256, 0, stream>>>(keyout, oslot, psums, (float4*)out_rows, valid);
}